// Round 4
// baseline (97.196 us; speedup 1.0000x reference)
//
#include <hip/hip_runtime.h>
#include <math.h>

#define KK 32
#define DD 256
#define QQ 16
#define NN 8192
#define LOG2PI 1.8378770664093453f
#define NCT 36            // padded col-tiles: 576 cols = 512 z + 32 xmu + 32 pad
#define CPW 9             // col-tiles per wave (4 waves x 9 = 36)

typedef __attribute__((ext_vector_type(8))) short short8v;
typedef __attribute__((ext_vector_type(4))) float float4v;

__device__ __forceinline__ unsigned short f2bf(float f) {
    union { float f; unsigned int u; } v; v.f = f;
    unsigned int u = v.u;
    return (unsigned short)((u + 0x7FFFu + ((u >> 16) & 1u)) >> 16);  // RNE
}

// ---------------- Kernel 1: per-component precompute (one block per k) ----
// Identical to R3 (verified; ~4 us).
__global__ __launch_bounds__(256) void mfa_setup_k(
    const float* __restrict__ log_pi,
    const float* __restrict__ mu,       // [K][D]
    const float* __restrict__ Lambda,   // [K][D][Q]
    const float* __restrict__ log_psi,  // [D]
    unsigned short* __restrict__ Wb,
    float* __restrict__ constk2,        // [K]
    float* __restrict__ wvec)           // [K][Q]
{
    __shared__ float inv_a_s[DD];
    __shared__ float Ls[DD][QQ];
    __shared__ float Lsia[DD][QQ];
    __shared__ float Ms[QQ][QQ + 1];
    __shared__ float Lc[QQ][QQ + 1];
    __shared__ float red_lg[4], red_m2[4], redq[4][QQ];
    __shared__ float sum_log_a_s, mu2a_s, ld_s;

    const int k = blockIdx.x;
    const int tid = threadIdx.x;
    const int wv = tid >> 6;

    const float a = expf(log_psi[tid]) + 1e-6f + 1e-5f;
    const float ia = 1.0f / a;
    inv_a_s[tid] = ia;
    const float mud = mu[k * DD + tid];

    float lg = logf(a);
    float m2 = mud * mud * ia;
    #pragma unroll
    for (int off = 32; off; off >>= 1) {
        lg += __shfl_down(lg, off, 64);
        m2 += __shfl_down(m2, off, 64);
    }
    if ((tid & 63) == 0) { red_lg[wv] = lg; red_m2[wv] = m2; }

    const float* Lk = Lambda + (size_t)k * DD * QQ;
    for (int i = tid; i < DD * QQ; i += 256) Ls[i >> 4][i & 15] = Lk[i];
    __syncthreads();

    #pragma unroll
    for (int q = 0; q < QQ; ++q) Lsia[tid][q] = Ls[tid][q] * ia;
    if (tid == 0) {
        sum_log_a_s = red_lg[0] + red_lg[1] + red_lg[2] + red_lg[3];
        mu2a_s      = red_m2[0] + red_m2[1] + red_m2[2] + red_m2[3];
    }
    __syncthreads();

    {
        const int q1 = tid >> 4, q2 = tid & 15;
        float b = 0.f;
        for (int d = 0; d < DD; ++d) b = fmaf(Lsia[d][q1], Ls[d][q2], b);
        Ms[q1][q2] = b + (q1 == q2 ? 1.0f : 0.0f);
    }
    __syncthreads();

    if (tid < QQ) {
        const int i = tid;
        float mrow[QQ];
        #pragma unroll
        for (int j = 0; j < QQ; ++j) mrow[j] = Ms[i][j];
        float l[QQ];
        float ldiag = 0.f;
        #pragma unroll
        for (int j = 0; j < QQ; ++j) {
            float s = mrow[j];
            #pragma unroll
            for (int t = 0; t < QQ; ++t) {
                if (t < j) s = fmaf(-l[t], __shfl(l[t], j, 64), s);
            }
            const float piv = __shfl(s, j, 64);
            const float ljj = sqrtf(piv);
            const float val = s / ljj;
            l[j] = (i == j) ? ljj : ((i > j) ? val : 0.f);
            if (i == j) ldiag = logf(ljj);
        }
        #pragma unroll
        for (int j = 0; j < QQ; ++j) Lc[i][j] = l[j];
        #pragma unroll
        for (int mask = 1; mask <= 8; mask <<= 1) ldiag += __shfl_xor(ldiag, mask, 64);
        if (i == 0) ld_s = ldiag;
    }
    __syncthreads();

    if (tid == 0) {
        const float logdetC = sum_log_a_s + 2.0f * ld_s;
        constk2[k] = log_pi[k] - 0.5f * ((float)DD * LOG2PI + logdetC + mu2a_s);
    }

    float tv[QQ];
    {
        float y[QQ];
        #pragma unroll
        for (int q = 0; q < QQ; ++q) {
            float s = Ls[tid][q];
            #pragma unroll
            for (int m = 0; m < QQ; ++m) {
                if (m < q) s = fmaf(-Lc[q][m], y[m], s);
            }
            y[q] = s / Lc[q][q];
        }
        #pragma unroll
        for (int q = 0; q < QQ; ++q) tv[q] = y[q] * ia;
    }

    #pragma unroll
    for (int q = 0; q < QQ; ++q) {
        float v = tv[q] * mud;
        #pragma unroll
        for (int off = 32; off; off >>= 1) v += __shfl_down(v, off, 64);
        if ((tid & 63) == 0) redq[wv][q] = v;
    }
    __syncthreads();
    if (tid < QQ) wvec[k * QQ + tid] = redq[0][tid] + redq[1][tid] + redq[2][tid] + redq[3][tid];

    {
        const int d = tid;
        const int kt = d >> 5, l_hi = (d >> 3) & 3, j = d & 7;
        #pragma unroll
        for (int q = 0; q < QQ; ++q) {
            const size_t idx = (((size_t)(kt * NCT + k) * 64) + l_hi * 16 + q) * 8 + j;
            Wb[idx] = f2bf(tv[q]);
        }
        const size_t idx = (((size_t)(kt * NCT + 32 + (k >> 4)) * 64) + l_hi * 16 + (k & 15)) * 8 + j;
        Wb[idx] = f2bf(mud * ia);
    }
    if (k < 2) {
        for (int i = tid; i < 512; i += 256) {
            const int kt = i >> 6, lane = i & 63;
            const size_t base = ((size_t)(kt * NCT + 34 + k) * 64 + lane) * 8;
            #pragma unroll
            for (int j = 0; j < 8; ++j) Wb[base + j] = 0;
        }
    }
}

// ---------------- Kernel 2: fused GEMM + epilogue, 32 rows/block ----------
// Grid 256 (1 block/CU). Wave w: 2 row-tiles x col-tiles [9w, 9w+9).
// A/B double-buffered prefetch across kt to hide L2 latency at 1 wave/SIMD.
__global__ __launch_bounds__(256, 1) void mfa_gemm_fused(
    const float* __restrict__ X,        // [N][D]
    const float* __restrict__ log_psi,  // [D]
    const unsigned short* __restrict__ Wb,
    const float* __restrict__ constk2,
    const float* __restrict__ wvec,     // [K][Q]
    float* __restrict__ out)            // [N*K] then [N]
{
    __shared__ short As[16 * 64 * 8];   // bf16 A-frags [g=kt*2+rt][lane][8], 16 KB
    __shared__ float inv_a_s[DD];
    __shared__ float w_s[KK][QQ];
    __shared__ float ck_s[KK];
    __shared__ float sx_s[32];
    __shared__ float corr_s[32][KK + 1];
    __shared__ float xmu_s[32][KK + 1];

    const int tid = threadIdx.x;
    const int lane = tid & 63, wv = tid >> 6;
    const int r0 = blockIdx.x * 32;

    inv_a_s[tid] = 1.0f / (expf(log_psi[tid]) + 1e-6f + 1e-5f);
    if (tid < KK) ck_s[tid] = constk2[tid];
    for (int i = tid; i < KK * QQ; i += 256) ((float*)w_s)[i] = wvec[i];

    // sx[n] = sum_d x^2 * inv_a (f32): 8 threads/row, coalesced (warms L1/L2)
    {
        const int n = tid >> 3, part = tid & 7;
        const float4* xp = (const float4*)(X + (size_t)(r0 + n) * DD + part * 32);
        float s = 0.f;
        #pragma unroll
        for (int i = 0; i < 8; ++i) {
            const float4 v = xp[i];
            const int d = part * 32 + i * 4;
            s = fmaf(v.x * inv_a_s[d + 0], v.x, s);
            s = fmaf(v.y * inv_a_s[d + 1], v.y, s);
            s = fmaf(v.z * inv_a_s[d + 2], v.z, s);
            s = fmaf(v.w * inv_a_s[d + 3], v.w, s);
        }
        s += __shfl_xor(s, 1, 64);
        s += __shfl_xor(s, 2, 64);
        s += __shfl_xor(s, 4, 64);
        if (part == 0) sx_s[n] = s;
    }

    // stage X tile -> bf16 A-frag layout (1024 chunks of 8 elems)
    #pragma unroll
    for (int rep = 0; rep < 4; ++rep) {
        const int c = tid + rep * 256;
        const int g = c >> 6;                   // kt*2 + rt, 0..15
        const int kt = g >> 1, rt = g & 1, lc = c & 63;
        const int row = r0 + rt * 16 + (lc & 15);
        const int d0 = kt * 32 + ((lc >> 4) & 3) * 8;
        const float4* xp = (const float4*)(X + (size_t)row * DD + d0);
        const float4 x0 = xp[0], x1 = xp[1];
        short8v av;
        av[0] = (short)f2bf(x0.x); av[1] = (short)f2bf(x0.y);
        av[2] = (short)f2bf(x0.z); av[3] = (short)f2bf(x0.w);
        av[4] = (short)f2bf(x1.x); av[5] = (short)f2bf(x1.y);
        av[6] = (short)f2bf(x1.z); av[7] = (short)f2bf(x1.w);
        *(short8v*)&As[(size_t)(g * 64 + lc) * 8] = av;
    }
    __syncthreads();

    // MFMA K-loop with A/B prefetch (double buffer across kt)
    const int sw = wv * CPW;
    float4v acc[2][CPW];
    #pragma unroll
    for (int rt = 0; rt < 2; ++rt)
        #pragma unroll
        for (int ct = 0; ct < CPW; ++ct)
            #pragma unroll
            for (int r = 0; r < 4; ++r) acc[rt][ct][r] = 0.f;

    const short8v* Asv = (const short8v*)As;
    const short8v* WpL = (const short8v*)Wb + lane;

    short8v a_cur[2], a_nxt[2], b_cur[CPW], b_nxt[CPW];
    a_cur[0] = Asv[0 * 64 + lane];
    a_cur[1] = Asv[1 * 64 + lane];
    #pragma unroll
    for (int ct = 0; ct < CPW; ++ct) b_cur[ct] = WpL[(size_t)(sw + ct) * 64];

    #pragma unroll
    for (int kt = 0; kt < 8; ++kt) {
        if (kt < 7) {
            #pragma unroll
            for (int ct = 0; ct < CPW; ++ct)
                b_nxt[ct] = WpL[(size_t)((kt + 1) * NCT + sw + ct) * 64];
            a_nxt[0] = Asv[((kt + 1) * 2 + 0) * 64 + lane];
            a_nxt[1] = Asv[((kt + 1) * 2 + 1) * 64 + lane];
        }
        #pragma unroll
        for (int ct = 0; ct < CPW; ++ct) {
            acc[0][ct] = __builtin_amdgcn_mfma_f32_16x16x32_bf16(a_cur[0], b_cur[ct], acc[0][ct], 0, 0, 0);
            acc[1][ct] = __builtin_amdgcn_mfma_f32_16x16x32_bf16(a_cur[1], b_cur[ct], acc[1][ct], 0, 0, 0);
        }
        if (kt < 7) {
            a_cur[0] = a_nxt[0]; a_cur[1] = a_nxt[1];
            #pragma unroll
            for (int ct = 0; ct < CPW; ++ct) b_cur[ct] = b_nxt[ct];
        }
    }

    // in-register epilogue: corr via 16-lane butterfly; xmu direct
    #pragma unroll
    for (int ct = 0; ct < CPW; ++ct) {
        const int cti = sw + ct;                // wave-uniform
        if (cti < 32) {
            const float w = w_s[cti][lane & 15];
            #pragma unroll
            for (int rt = 0; rt < 2; ++rt) {
                float q0 = acc[rt][ct][0] - w, q1 = acc[rt][ct][1] - w,
                      q2 = acc[rt][ct][2] - w, q3 = acc[rt][ct][3] - w;
                q0 *= q0; q1 *= q1; q2 *= q2; q3 *= q3;
                #pragma unroll
                for (int mask = 1; mask <= 8; mask <<= 1) {
                    q0 += __shfl_xor(q0, mask, 64);
                    q1 += __shfl_xor(q1, mask, 64);
                    q2 += __shfl_xor(q2, mask, 64);
                    q3 += __shfl_xor(q3, mask, 64);
                }
                if ((lane & 15) == 0) {
                    const int nb = rt * 16 + (lane >> 4) * 4;
                    corr_s[nb + 0][cti] = q0; corr_s[nb + 1][cti] = q1;
                    corr_s[nb + 2][cti] = q2; corr_s[nb + 3][cti] = q3;
                }
            }
        } else if (cti < 34) {
            const int kk2 = (cti - 32) * 16 + (lane & 15);
            #pragma unroll
            for (int rt = 0; rt < 2; ++rt) {
                const int nb = rt * 16 + (lane >> 4) * 4;
                xmu_s[nb + 0][kk2] = acc[rt][ct][0];
                xmu_s[nb + 1][kk2] = acc[rt][ct][1];
                xmu_s[nb + 2][kk2] = acc[rt][ct][2];
                xmu_s[nb + 3][kk2] = acc[rt][ct][3];
            }
        }
    }
    __syncthreads();

    // logsumexp + output, one thread per row
    if (tid < 32) {
        const int n = tid;
        const float sxh = 0.5f * sx_s[n];
        float lp[KK];
        float m = -INFINITY;
        #pragma unroll
        for (int k = 0; k < KK; ++k) {
            const float v = ck_s[k] - sxh + xmu_s[n][k] + 0.5f * corr_s[n][k];
            lp[k] = v;
            m = fmaxf(m, v);
        }
        float sum = 0.f;
        #pragma unroll
        for (int k = 0; k < KK; ++k) sum += expf(lp[k] - m);
        const float lse = m + logf(sum);
        float4* o = (float4*)(out + (size_t)(r0 + n) * KK);
        #pragma unroll
        for (int k4 = 0; k4 < KK / 4; ++k4)
            o[k4] = make_float4(lp[4 * k4 + 0] - lse, lp[4 * k4 + 1] - lse,
                                lp[4 * k4 + 2] - lse, lp[4 * k4 + 3] - lse);
        out[(size_t)NN * KK + r0 + n] = lse;
    }
}

extern "C" void kernel_launch(void* const* d_in, const int* in_sizes, int n_in,
                              void* d_out, int out_size, void* d_ws, size_t ws_size,
                              hipStream_t stream) {
    const float* X       = (const float*)d_in[0];
    const float* log_pi  = (const float*)d_in[1];
    const float* mu      = (const float*)d_in[2];
    const float* Lambda  = (const float*)d_in[3];
    const float* log_psi = (const float*)d_in[4];
    float* out = (float*)d_out;

    unsigned short* Wb = (unsigned short*)d_ws;            // 8*36*64*8*2 = 294912 B
    float* constk2 = (float*)((char*)d_ws + 294912);
    float* wvec    = constk2 + KK;

    mfa_setup_k<<<KK, 256, 0, stream>>>(log_pi, mu, Lambda, log_psi, Wb, constk2, wvec);
    mfa_gemm_fused<<<NN / 32, 256, 0, stream>>>(X, log_psi, Wb, constk2, wvec, out);
}

// Round 6
// 96.129 us; speedup vs baseline: 1.0111x; 1.0111x over previous
//
#include <hip/hip_runtime.h>
#include <math.h>

#define KK 32
#define DD 256
#define QQ 16
#define NN 8192
#define LOG2PI 1.8378770664093453f
#define NCT 36            // padded col-tiles: 576 cols = 512 z + 32 xmu + 32 pad
#define CPW 9             // col-tiles per col-wave-group (4 groups x 9 = 36)

typedef __attribute__((ext_vector_type(8))) short short8v;
typedef __attribute__((ext_vector_type(4))) float float4v;

__device__ __forceinline__ unsigned short f2bf(float f) {
    union { float f; unsigned int u; } v; v.f = f;
    unsigned int u = v.u;
    return (unsigned short)((u + 0x7FFFu + ((u >> 16) & 1u)) >> 16);  // RNE
}

// ---------------- Kernel 1: per-component precompute (one block per k) ----
// Identical to R3 (verified; ~4 us).
__global__ __launch_bounds__(256) void mfa_setup_k(
    const float* __restrict__ log_pi,
    const float* __restrict__ mu,       // [K][D]
    const float* __restrict__ Lambda,   // [K][D][Q]
    const float* __restrict__ log_psi,  // [D]
    unsigned short* __restrict__ Wb,
    float* __restrict__ constk2,        // [K]
    float* __restrict__ wvec)           // [K][Q]
{
    __shared__ float inv_a_s[DD];
    __shared__ float Ls[DD][QQ];
    __shared__ float Lsia[DD][QQ];
    __shared__ float Ms[QQ][QQ + 1];
    __shared__ float Lc[QQ][QQ + 1];
    __shared__ float red_lg[4], red_m2[4], redq[4][QQ];
    __shared__ float sum_log_a_s, mu2a_s, ld_s;

    const int k = blockIdx.x;
    const int tid = threadIdx.x;
    const int wv = tid >> 6;

    const float a = expf(log_psi[tid]) + 1e-6f + 1e-5f;
    const float ia = 1.0f / a;
    inv_a_s[tid] = ia;
    const float mud = mu[k * DD + tid];

    float lg = logf(a);
    float m2 = mud * mud * ia;
    #pragma unroll
    for (int off = 32; off; off >>= 1) {
        lg += __shfl_down(lg, off, 64);
        m2 += __shfl_down(m2, off, 64);
    }
    if ((tid & 63) == 0) { red_lg[wv] = lg; red_m2[wv] = m2; }

    const float* Lk = Lambda + (size_t)k * DD * QQ;
    for (int i = tid; i < DD * QQ; i += 256) Ls[i >> 4][i & 15] = Lk[i];
    __syncthreads();

    #pragma unroll
    for (int q = 0; q < QQ; ++q) Lsia[tid][q] = Ls[tid][q] * ia;
    if (tid == 0) {
        sum_log_a_s = red_lg[0] + red_lg[1] + red_lg[2] + red_lg[3];
        mu2a_s      = red_m2[0] + red_m2[1] + red_m2[2] + red_m2[3];
    }
    __syncthreads();

    {
        const int q1 = tid >> 4, q2 = tid & 15;
        float b = 0.f;
        for (int d = 0; d < DD; ++d) b = fmaf(Lsia[d][q1], Ls[d][q2], b);
        Ms[q1][q2] = b + (q1 == q2 ? 1.0f : 0.0f);
    }
    __syncthreads();

    if (tid < QQ) {
        const int i = tid;
        float mrow[QQ];
        #pragma unroll
        for (int j = 0; j < QQ; ++j) mrow[j] = Ms[i][j];
        float l[QQ];
        float ldiag = 0.f;
        #pragma unroll
        for (int j = 0; j < QQ; ++j) {
            float s = mrow[j];
            #pragma unroll
            for (int t = 0; t < QQ; ++t) {
                if (t < j) s = fmaf(-l[t], __shfl(l[t], j, 64), s);
            }
            const float piv = __shfl(s, j, 64);
            const float ljj = sqrtf(piv);
            const float val = s / ljj;
            l[j] = (i == j) ? ljj : ((i > j) ? val : 0.f);
            if (i == j) ldiag = logf(ljj);
        }
        #pragma unroll
        for (int j = 0; j < QQ; ++j) Lc[i][j] = l[j];
        #pragma unroll
        for (int mask = 1; mask <= 8; mask <<= 1) ldiag += __shfl_xor(ldiag, mask, 64);
        if (i == 0) ld_s = ldiag;
    }
    __syncthreads();

    if (tid == 0) {
        const float logdetC = sum_log_a_s + 2.0f * ld_s;
        constk2[k] = log_pi[k] - 0.5f * ((float)DD * LOG2PI + logdetC + mu2a_s);
    }

    float tv[QQ];
    {
        float y[QQ];
        #pragma unroll
        for (int q = 0; q < QQ; ++q) {
            float s = Ls[tid][q];
            #pragma unroll
            for (int m = 0; m < QQ; ++m) {
                if (m < q) s = fmaf(-Lc[q][m], y[m], s);
            }
            y[q] = s / Lc[q][q];
        }
        #pragma unroll
        for (int q = 0; q < QQ; ++q) tv[q] = y[q] * ia;
    }

    #pragma unroll
    for (int q = 0; q < QQ; ++q) {
        float v = tv[q] * mud;
        #pragma unroll
        for (int off = 32; off; off >>= 1) v += __shfl_down(v, off, 64);
        if ((tid & 63) == 0) redq[wv][q] = v;
    }
    __syncthreads();
    if (tid < QQ) wvec[k * QQ + tid] = redq[0][tid] + redq[1][tid] + redq[2][tid] + redq[3][tid];

    {
        const int d = tid;
        const int kt = d >> 5, l_hi = (d >> 3) & 3, j = d & 7;
        #pragma unroll
        for (int q = 0; q < QQ; ++q) {
            const size_t idx = (((size_t)(kt * NCT + k) * 64) + l_hi * 16 + q) * 8 + j;
            Wb[idx] = f2bf(tv[q]);
        }
        const size_t idx = (((size_t)(kt * NCT + 32 + (k >> 4)) * 64) + l_hi * 16 + (k & 15)) * 8 + j;
        Wb[idx] = f2bf(mud * ia);
    }
    if (k < 2) {
        for (int i = tid; i < 512; i += 256) {
            const int kt = i >> 6, lane = i & 63;
            const size_t base = ((size_t)(kt * NCT + 34 + k) * 64 + lane) * 8;
            #pragma unroll
            for (int j = 0; j < 8; ++j) Wb[base + j] = 0;
        }
    }
}

// ---------------- Kernel 2: fused GEMM, 32 rows/block, 512 threads --------
// Grid 256, 8 waves/block = 2 waves/SIMD with wave-pairs sharing B col-tiles.
// R6 fix: barrier between inv_a_s population and its cross-wave readers.
__global__ __launch_bounds__(512, 2) void mfa_gemm_fused(
    const float* __restrict__ X,        // [N][D]
    const float* __restrict__ log_psi,  // [D]
    const unsigned short* __restrict__ Wb,
    const float* __restrict__ constk2,
    const float* __restrict__ wvec,     // [K][Q]
    float* __restrict__ out)            // [N*K] then [N]
{
    __shared__ short As[16 * 64 * 8];   // bf16 A-frags [g=kt*2+rt][lane][8], 16 KB
    __shared__ float inv_a_s[DD];
    __shared__ float w_s[KK][QQ];
    __shared__ float ck_s[KK];
    __shared__ float sx_s[32];
    __shared__ float corr_s[32][KK + 1];
    __shared__ float xmu_s[32][KK + 1];

    const int tid = threadIdx.x;
    const int lane = tid & 63, wv = tid >> 6;   // wv in [0,8)
    const int rt = wv & 1;                      // row-tile of this wave
    const int sw = (wv >> 1) * CPW;             // col-tile start
    const int r0 = blockIdx.x * 32;

    if (tid < DD) inv_a_s[tid] = 1.0f / (expf(log_psi[tid]) + 1e-6f + 1e-5f);
    if (tid < KK) ck_s[tid] = constk2[tid];
    if (tid < KK * QQ) ((float*)w_s)[tid] = wvec[tid];
    __syncthreads();   // inv_a_s/ck_s/w_s visible to all waves (R5 race fix)

    // sx[n] = sum_d x^2 * inv_a (f32): 16 threads/row, coalesced
    {
        const int n = tid >> 4, part = tid & 15;
        const float4* xp = (const float4*)(X + (size_t)(r0 + n) * DD + part * 16);
        float s = 0.f;
        #pragma unroll
        for (int i = 0; i < 4; ++i) {
            const float4 v = xp[i];
            const int d = part * 16 + i * 4;
            s = fmaf(v.x * inv_a_s[d + 0], v.x, s);
            s = fmaf(v.y * inv_a_s[d + 1], v.y, s);
            s = fmaf(v.z * inv_a_s[d + 2], v.z, s);
            s = fmaf(v.w * inv_a_s[d + 3], v.w, s);
        }
        s += __shfl_xor(s, 1, 64);
        s += __shfl_xor(s, 2, 64);
        s += __shfl_xor(s, 4, 64);
        s += __shfl_xor(s, 8, 64);
        if (part == 0) sx_s[n] = s;
    }

    // stage X tile -> bf16 A-frag layout (1024 chunks of 8 elems, 2 reps)
    #pragma unroll
    for (int rep = 0; rep < 2; ++rep) {
        const int c = tid + rep * 512;
        const int g = c >> 6;                   // kt*2 + rts, 0..15
        const int kt = g >> 1, rts = g & 1, lc = c & 63;
        const int row = r0 + rts * 16 + (lc & 15);
        const int d0 = kt * 32 + ((lc >> 4) & 3) * 8;
        const float4* xp = (const float4*)(X + (size_t)row * DD + d0);
        const float4 x0 = xp[0], x1 = xp[1];
        short8v av;
        av[0] = (short)f2bf(x0.x); av[1] = (short)f2bf(x0.y);
        av[2] = (short)f2bf(x0.z); av[3] = (short)f2bf(x0.w);
        av[4] = (short)f2bf(x1.x); av[5] = (short)f2bf(x1.y);
        av[6] = (short)f2bf(x1.z); av[7] = (short)f2bf(x1.w);
        *(short8v*)&As[(size_t)(g * 64 + lc) * 8] = av;
    }
    __syncthreads();

    // MFMA K-loop: A from LDS, B from global (wave-pairs share B lines)
    float4v acc[CPW];
    #pragma unroll
    for (int ct = 0; ct < CPW; ++ct)
        #pragma unroll
        for (int r = 0; r < 4; ++r) acc[ct][r] = 0.f;

    const short8v* Asv = (const short8v*)As;
    const short8v* WpL = (const short8v*)Wb + lane;

    #pragma unroll
    for (int kt = 0; kt < 8; ++kt) {
        const short8v a = Asv[(kt * 2 + rt) * 64 + lane];
        #pragma unroll
        for (int ct = 0; ct < CPW; ++ct) {
            const short8v bf = WpL[(size_t)(kt * NCT + sw + ct) * 64];
            acc[ct] = __builtin_amdgcn_mfma_f32_16x16x32_bf16(a, bf, acc[ct], 0, 0, 0);
        }
    }

    // in-register epilogue: corr via 16-lane butterfly; xmu direct
    #pragma unroll
    for (int ct = 0; ct < CPW; ++ct) {
        const int cti = sw + ct;                // wave-uniform
        if (cti < 32) {
            const float w = w_s[cti][lane & 15];
            float q0 = acc[ct][0] - w, q1 = acc[ct][1] - w,
                  q2 = acc[ct][2] - w, q3 = acc[ct][3] - w;
            q0 *= q0; q1 *= q1; q2 *= q2; q3 *= q3;
            #pragma unroll
            for (int mask = 1; mask <= 8; mask <<= 1) {
                q0 += __shfl_xor(q0, mask, 64);
                q1 += __shfl_xor(q1, mask, 64);
                q2 += __shfl_xor(q2, mask, 64);
                q3 += __shfl_xor(q3, mask, 64);
            }
            if ((lane & 15) == 0) {
                const int nb = rt * 16 + (lane >> 4) * 4;
                corr_s[nb + 0][cti] = q0; corr_s[nb + 1][cti] = q1;
                corr_s[nb + 2][cti] = q2; corr_s[nb + 3][cti] = q3;
            }
        } else if (cti < 34) {
            const int kk2 = (cti - 32) * 16 + (lane & 15);
            const int nb = rt * 16 + (lane >> 4) * 4;
            xmu_s[nb + 0][kk2] = acc[ct][0]; xmu_s[nb + 1][kk2] = acc[ct][1];
            xmu_s[nb + 2][kk2] = acc[ct][2]; xmu_s[nb + 3][kk2] = acc[ct][3];
        }
    }
    __syncthreads();

    // logsumexp + output, one thread per row
    if (tid < 32) {
        const int n = tid;
        const float sxh = 0.5f * sx_s[n];
        float lp[KK];
        float m = -INFINITY;
        #pragma unroll
        for (int k = 0; k < KK; ++k) {
            const float v = ck_s[k] - sxh + xmu_s[n][k] + 0.5f * corr_s[n][k];
            lp[k] = v;
            m = fmaxf(m, v);
        }
        float sum = 0.f;
        #pragma unroll
        for (int k = 0; k < KK; ++k) sum += expf(lp[k] - m);
        const float lse = m + logf(sum);
        float4* o = (float4*)(out + (size_t)(r0 + n) * KK);
        #pragma unroll
        for (int k4 = 0; k4 < KK / 4; ++k4)
            o[k4] = make_float4(lp[4 * k4 + 0] - lse, lp[4 * k4 + 1] - lse,
                                lp[4 * k4 + 2] - lse, lp[4 * k4 + 3] - lse);
        out[(size_t)NN * KK + r0 + n] = lse;
    }
}

extern "C" void kernel_launch(void* const* d_in, const int* in_sizes, int n_in,
                              void* d_out, int out_size, void* d_ws, size_t ws_size,
                              hipStream_t stream) {
    const float* X       = (const float*)d_in[0];
    const float* log_pi  = (const float*)d_in[1];
    const float* mu      = (const float*)d_in[2];
    const float* Lambda  = (const float*)d_in[3];
    const float* log_psi = (const float*)d_in[4];
    float* out = (float*)d_out;

    unsigned short* Wb = (unsigned short*)d_ws;            // 8*36*64*8*2 = 294912 B
    float* constk2 = (float*)((char*)d_ws + 294912);
    float* wvec    = constk2 + KK;

    mfa_setup_k<<<KK, 256, 0, stream>>>(log_pi, mu, Lambda, log_psi, Wb, constk2, wvec);
    mfa_gemm_fused<<<NN / 32, 512, 0, stream>>>(X, log_psi, Wb, constk2, wvec, out);
}

// Round 7
// 94.274 us; speedup vs baseline: 1.0310x; 1.0197x over previous
//
#include <hip/hip_runtime.h>
#include <math.h>

#define KK 32
#define DD 256
#define QQ 16
#define NN 8192
#define LOG2PI 1.8378770664093453f
#define NCT 36            // padded col-tiles: 576 cols = 512 z + 32 xmu + 32 pad
#define CPW 9             // col-tiles per wave (4 waves x 9 = 36)

typedef __attribute__((ext_vector_type(8))) short short8v;
typedef __attribute__((ext_vector_type(4))) float float4v;

__device__ __forceinline__ unsigned short f2bf(float f) {
    union { float f; unsigned int u; } v; v.f = f;
    unsigned int u = v.u;
    return (unsigned short)((u + 0x7FFFu + ((u >> 16) & 1u)) >> 16);  // RNE
}

// ---------------- Kernel 1: per-component precompute (one block per k) ----
// Wave-parallel Cholesky + per-thread forward-solve; writes Wb (bf16 MFMA
// B-frag layout), constk2, wvec. Measured ~3-4 us.
__global__ __launch_bounds__(256) void mfa_setup_k(
    const float* __restrict__ log_pi,
    const float* __restrict__ mu,       // [K][D]
    const float* __restrict__ Lambda,   // [K][D][Q]
    const float* __restrict__ log_psi,  // [D]
    unsigned short* __restrict__ Wb,
    float* __restrict__ constk2,        // [K]
    float* __restrict__ wvec)           // [K][Q]
{
    __shared__ float inv_a_s[DD];
    __shared__ float Ls[DD][QQ];
    __shared__ float Lsia[DD][QQ];
    __shared__ float Ms[QQ][QQ + 1];
    __shared__ float Lc[QQ][QQ + 1];
    __shared__ float red_lg[4], red_m2[4], redq[4][QQ];
    __shared__ float sum_log_a_s, mu2a_s, ld_s;

    const int k = blockIdx.x;
    const int tid = threadIdx.x;
    const int wv = tid >> 6;

    const float a = expf(log_psi[tid]) + 1e-6f + 1e-5f;
    const float ia = 1.0f / a;
    inv_a_s[tid] = ia;
    const float mud = mu[k * DD + tid];

    float lg = logf(a);
    float m2 = mud * mud * ia;
    #pragma unroll
    for (int off = 32; off; off >>= 1) {
        lg += __shfl_down(lg, off, 64);
        m2 += __shfl_down(m2, off, 64);
    }
    if ((tid & 63) == 0) { red_lg[wv] = lg; red_m2[wv] = m2; }

    const float* Lk = Lambda + (size_t)k * DD * QQ;
    for (int i = tid; i < DD * QQ; i += 256) Ls[i >> 4][i & 15] = Lk[i];
    __syncthreads();

    #pragma unroll
    for (int q = 0; q < QQ; ++q) Lsia[tid][q] = Ls[tid][q] * ia;
    if (tid == 0) {
        sum_log_a_s = red_lg[0] + red_lg[1] + red_lg[2] + red_lg[3];
        mu2a_s      = red_m2[0] + red_m2[1] + red_m2[2] + red_m2[3];
    }
    __syncthreads();

    {
        const int q1 = tid >> 4, q2 = tid & 15;
        float b = 0.f;
        for (int d = 0; d < DD; ++d) b = fmaf(Lsia[d][q1], Ls[d][q2], b);
        Ms[q1][q2] = b + (q1 == q2 ? 1.0f : 0.0f);
    }
    __syncthreads();

    // Register-resident shuffle Cholesky, lanes 0..15 of wave 0, no barriers.
    if (tid < QQ) {
        const int i = tid;
        float mrow[QQ];
        #pragma unroll
        for (int j = 0; j < QQ; ++j) mrow[j] = Ms[i][j];
        float l[QQ];
        float ldiag = 0.f;
        #pragma unroll
        for (int j = 0; j < QQ; ++j) {
            float s = mrow[j];
            #pragma unroll
            for (int t = 0; t < QQ; ++t) {
                if (t < j) s = fmaf(-l[t], __shfl(l[t], j, 64), s);
            }
            const float piv = __shfl(s, j, 64);
            const float ljj = sqrtf(piv);
            const float val = s / ljj;
            l[j] = (i == j) ? ljj : ((i > j) ? val : 0.f);
            if (i == j) ldiag = logf(ljj);
        }
        #pragma unroll
        for (int j = 0; j < QQ; ++j) Lc[i][j] = l[j];
        #pragma unroll
        for (int mask = 1; mask <= 8; mask <<= 1) ldiag += __shfl_xor(ldiag, mask, 64);
        if (i == 0) ld_s = ldiag;
    }
    __syncthreads();

    if (tid == 0) {
        const float logdetC = sum_log_a_s + 2.0f * ld_s;
        constk2[k] = log_pi[k] - 0.5f * ((float)DD * LOG2PI + logdetC + mu2a_s);
    }

    // Forward-solve L y = Lambda[d,:]^T per thread d; tv = y * ia[d].
    float tv[QQ];
    {
        float y[QQ];
        #pragma unroll
        for (int q = 0; q < QQ; ++q) {
            float s = Ls[tid][q];
            #pragma unroll
            for (int m = 0; m < QQ; ++m) {
                if (m < q) s = fmaf(-Lc[q][m], y[m], s);
            }
            y[q] = s / Lc[q][q];
        }
        #pragma unroll
        for (int q = 0; q < QQ; ++q) tv[q] = y[q] * ia;
    }

    // w_kq = sum_d tv[q] * mu[k][d]
    #pragma unroll
    for (int q = 0; q < QQ; ++q) {
        float v = tv[q] * mud;
        #pragma unroll
        for (int off = 32; off; off >>= 1) v += __shfl_down(v, off, 64);
        if ((tid & 63) == 0) redq[wv][q] = v;
    }
    __syncthreads();
    if (tid < QQ) wvec[k * QQ + tid] = redq[0][tid] + redq[1][tid] + redq[2][tid] + redq[3][tid];

    // scatter into Wb fragment layout (bf16)
    {
        const int d = tid;
        const int kt = d >> 5, l_hi = (d >> 3) & 3, j = d & 7;
        #pragma unroll
        for (int q = 0; q < QQ; ++q) {
            const size_t idx = (((size_t)(kt * NCT + k) * 64) + l_hi * 16 + q) * 8 + j;
            Wb[idx] = f2bf(tv[q]);
        }
        const size_t idx = (((size_t)(kt * NCT + 32 + (k >> 4)) * 64) + l_hi * 16 + (k & 15)) * 8 + j;
        Wb[idx] = f2bf(mud * ia);
    }
    if (k < 2) {
        for (int i = tid; i < 512; i += 256) {
            const int kt = i >> 6, lane = i & 63;
            const size_t base = ((size_t)(kt * NCT + 34 + k) * 64 + lane) * 8;
            #pragma unroll
            for (int j = 0; j < 8; ++j) Wb[base + j] = 0;
        }
    }
}

// ---------------- Kernel 2: fused GEMM + in-register epilogue ------------
// Block: 16 rows x 576 cols, 4 waves x 9 col-tiles; grid 512 (2 blocks/CU).
// Measured-best config (R3: 93.0 us total); R4/R6 variants (32 rows/block,
// 1 block/CU; 512-thr wave-pair B-sharing) both regressed ~3-4 us.
__global__ __launch_bounds__(256) void mfa_gemm_fused(
    const float* __restrict__ X,        // [N][D]
    const float* __restrict__ log_psi,  // [D]
    const unsigned short* __restrict__ Wb,
    const float* __restrict__ constk2,
    const float* __restrict__ wvec,     // [K][Q]
    float* __restrict__ out)            // [N*K] then [N]
{
    __shared__ short As[8 * 64 * 8];    // bf16 A-frags, 8 KB
    __shared__ float inv_a_s[DD];
    __shared__ float w_s[KK][QQ];
    __shared__ float ck_s[KK];
    __shared__ float sx_s[16];
    __shared__ float corr_s[16][KK + 1];
    __shared__ float xmu_s[16][KK + 1];

    const int tid = threadIdx.x;
    const int lane = tid & 63, wv = tid >> 6;
    const int r0 = blockIdx.x * 16;

    inv_a_s[tid] = 1.0f / (expf(log_psi[tid]) + 1e-6f + 1e-5f);
    if (tid < KK) ck_s[tid] = constk2[tid];
    for (int i = tid; i < KK * QQ; i += 256) ((float*)w_s)[i] = wvec[i];

    // stage X tile -> bf16 A-frag layout (convert once per block)
    #pragma unroll
    for (int rep = 0; rep < 2; ++rep) {
        const int c = tid + rep * 256;          // chunk = (kt, lane_c)
        const int kt = c >> 6, lc = c & 63;
        const int m = lc & 15, d0 = kt * 32 + ((lc >> 4) & 3) * 8;
        const float4* xp = (const float4*)(X + (size_t)(r0 + m) * DD + d0);
        const float4 x0 = xp[0], x1 = xp[1];
        short8v av;
        av[0] = (short)f2bf(x0.x); av[1] = (short)f2bf(x0.y);
        av[2] = (short)f2bf(x0.z); av[3] = (short)f2bf(x0.w);
        av[4] = (short)f2bf(x1.x); av[5] = (short)f2bf(x1.y);
        av[6] = (short)f2bf(x1.z); av[7] = (short)f2bf(x1.w);
        *(short8v*)&As[(size_t)(kt * 64 + lc) * 8] = av;
    }
    __syncthreads();

    // MFMA K-loop: A from LDS (ds_read_b128), B from global (L2-resident)
    const int sw = wv * CPW;
    float4v acc[CPW];
    #pragma unroll
    for (int ct = 0; ct < CPW; ++ct)
        #pragma unroll
        for (int r = 0; r < 4; ++r) acc[ct][r] = 0.f;

    #pragma unroll
    for (int kt = 0; kt < 8; ++kt) {
        const short8v a = *(const short8v*)&As[(size_t)(kt * 64 + lane) * 8];
        const short8v* Wp = (const short8v*)Wb + (size_t)(kt * NCT + sw) * 64 + lane;
        #pragma unroll
        for (int ct = 0; ct < CPW; ++ct) {
            const short8v bf = Wp[ct * 64];
            acc[ct] = __builtin_amdgcn_mfma_f32_16x16x32_bf16(a, bf, acc[ct], 0, 0, 0);
        }
    }

    // sx[n] = sum_d x^2 * inv_a (f32): 16 threads per row (after barrier,
    // inv_a_s safe: written by all 256 threads, read after __syncthreads)
    {
        const int n = tid >> 4, part = tid & 15;
        const float4* xp = (const float4*)(X + (size_t)(r0 + n) * DD + part * 16);
        float s = 0.f;
        #pragma unroll
        for (int i = 0; i < 4; ++i) {
            const float4 v = xp[i];
            const int d = part * 16 + i * 4;
            s = fmaf(v.x * inv_a_s[d + 0], v.x, s);
            s = fmaf(v.y * inv_a_s[d + 1], v.y, s);
            s = fmaf(v.z * inv_a_s[d + 2], v.z, s);
            s = fmaf(v.w * inv_a_s[d + 3], v.w, s);
        }
        s += __shfl_xor(s, 1, 64);
        s += __shfl_xor(s, 2, 64);
        s += __shfl_xor(s, 4, 64);
        s += __shfl_xor(s, 8, 64);
        if (part == 0) sx_s[n] = s;
    }

    // in-register epilogue: corr via 16-lane butterfly; xmu direct
    #pragma unroll
    for (int ct = 0; ct < CPW; ++ct) {
        const int cti = sw + ct;                // wave-uniform
        if (cti < 32) {
            const float w = w_s[cti][lane & 15];
            float q0 = acc[ct][0] - w, q1 = acc[ct][1] - w,
                  q2 = acc[ct][2] - w, q3 = acc[ct][3] - w;
            q0 *= q0; q1 *= q1; q2 *= q2; q3 *= q3;
            #pragma unroll
            for (int mask = 1; mask <= 8; mask <<= 1) {
                q0 += __shfl_xor(q0, mask, 64);
                q1 += __shfl_xor(q1, mask, 64);
                q2 += __shfl_xor(q2, mask, 64);
                q3 += __shfl_xor(q3, mask, 64);
            }
            if ((lane & 15) == 0) {
                const int nb = (lane >> 4) * 4;
                corr_s[nb + 0][cti] = q0; corr_s[nb + 1][cti] = q1;
                corr_s[nb + 2][cti] = q2; corr_s[nb + 3][cti] = q3;
            }
        } else if (cti < 34) {
            const int kk2 = (cti - 32) * 16 + (lane & 15);
            const int nb = (lane >> 4) * 4;
            xmu_s[nb + 0][kk2] = acc[ct][0]; xmu_s[nb + 1][kk2] = acc[ct][1];
            xmu_s[nb + 2][kk2] = acc[ct][2]; xmu_s[nb + 3][kk2] = acc[ct][3];
        }
    }
    __syncthreads();

    // logsumexp + output, one thread per row
    if (tid < 16) {
        const int n = tid;
        const float sxh = 0.5f * sx_s[n];
        float lp[KK];
        float m = -INFINITY;
        #pragma unroll
        for (int k = 0; k < KK; ++k) {
            const float v = ck_s[k] - sxh + xmu_s[n][k] + 0.5f * corr_s[n][k];
            lp[k] = v;
            m = fmaxf(m, v);
        }
        float sum = 0.f;
        #pragma unroll
        for (int k = 0; k < KK; ++k) sum += expf(lp[k] - m);
        const float lse = m + logf(sum);
        float4* o = (float4*)(out + (size_t)(r0 + n) * KK);
        #pragma unroll
        for (int k4 = 0; k4 < KK / 4; ++k4)
            o[k4] = make_float4(lp[4 * k4 + 0] - lse, lp[4 * k4 + 1] - lse,
                                lp[4 * k4 + 2] - lse, lp[4 * k4 + 3] - lse);
        out[(size_t)NN * KK + r0 + n] = lse;
    }
}

extern "C" void kernel_launch(void* const* d_in, const int* in_sizes, int n_in,
                              void* d_out, int out_size, void* d_ws, size_t ws_size,
                              hipStream_t stream) {
    const float* X       = (const float*)d_in[0];
    const float* log_pi  = (const float*)d_in[1];
    const float* mu      = (const float*)d_in[2];
    const float* Lambda  = (const float*)d_in[3];
    const float* log_psi = (const float*)d_in[4];
    float* out = (float*)d_out;

    unsigned short* Wb = (unsigned short*)d_ws;            // 8*36*64*8*2 = 294912 B
    float* constk2 = (float*)((char*)d_ws + 294912);
    float* wvec    = constk2 + KK;

    mfa_setup_k<<<KK, 256, 0, stream>>>(log_pi, mu, Lambda, log_psi, Wb, constk2, wvec);
    mfa_gemm_fused<<<NN / 16, 256, 0, stream>>>(X, log_psi, Wb, constk2, wvec, out);
}